// Round 1
// baseline (123.355 us; speedup 1.0000x reference)
//
#include <hip/hip_runtime.h>
#include <hip/hip_bf16.h>
#include <math.h>

// Problem constants
#define MM 12544   // 64 * 196 patches
#define KK 768     // 16*16*3
#define NN 768     // embedding dim
#define BM 128
#define BN 128
#define BK 64
#define KT 12      // KK/BK
#define MT 98      // MM/BM
#define NT 6       // NN/BN
#define TILE_BYTES (BM*BK*2)   // 16384

typedef __bf16 v8bf __attribute__((ext_vector_type(8)));
typedef float  v4f  __attribute__((ext_vector_type(4)));

// ---------------------------------------------------------------------------
// Phase 1a: im2col + fp32->bf16 + tile-pack with xor swizzle.
// A-pack layout: [mt 0..97][kt 0..11][r 0..127][g 0..7][8 bf16], where the
// stored group index is g ^ (r&7)  (breaks LDS bank conflicts in the GEMM's
// ds_read_b128 fragment reads; staging copies the tile verbatim so the
// swizzle survives global_load_lds's contiguous-copy constraint).
// One thread = one 8-element k-group = 2x float4 coalesced reads + 1x 16B store.
// 48 % 8 == 0 so an aligned 8-group never crosses an image-row chunk.
// ---------------------------------------------------------------------------
__global__ __launch_bounds__(256) void im2col_pack(const float* __restrict__ img,
                                                   __hip_bfloat16* __restrict__ apack) {
    int tid = blockIdx.x * 256 + threadIdx.x;   // 0 .. 12544*96-1
    int gg  = tid % 96;                         // k-group of 8 within row
    int m   = tid / 96;                         // patch index 0..12543
    int b   = m / 196;
    int pm  = m - b * 196;
    int pr  = pm / 14;
    int pc  = pm - pr * 14;
    int k0  = gg * 8;
    int i   = k0 / 48;                          // row within patch
    int rem = k0 - i * 48;                      // (j*3+c) offset, multiple of 8
    const float* src = img + (size_t)(((b * 224 + pr * 16 + i) * 224 + pc * 16) * 3 + rem);
    float4 f0 = *(const float4*)src;
    float4 f1 = *(const float4*)(src + 4);
    int mt = m >> 7;
    int r  = m & 127;
    int kt = gg >> 3;
    int g  = gg & 7;
    int gs = g ^ (r & 7);
    union { __hip_bfloat16 h[8]; uint4 u; } o;
    o.h[0] = __float2bfloat16(f0.x); o.h[1] = __float2bfloat16(f0.y);
    o.h[2] = __float2bfloat16(f0.z); o.h[3] = __float2bfloat16(f0.w);
    o.h[4] = __float2bfloat16(f1.x); o.h[5] = __float2bfloat16(f1.y);
    o.h[6] = __float2bfloat16(f1.z); o.h[7] = __float2bfloat16(f1.w);
    *(uint4*)(apack + ((size_t)(mt * KT + kt) * BM + r) * BK + gs * 8) = o.u;
}

// ---------------------------------------------------------------------------
// Phase 1b: W [K=768][N=768] fp32 -> Wt-pack [nt][kt][n 0..127][g^(n&7)][8] bf16.
// Thread = (n, k-group of 8): 8 coalesced-across-n strided reads, one 16B store.
// ---------------------------------------------------------------------------
__global__ __launch_bounds__(256) void wt_pack(const float* __restrict__ w,
                                               __hip_bfloat16* __restrict__ wpack) {
    int tid = blockIdx.x * 256 + threadIdx.x;   // 0 .. 768*96-1
    int n   = tid % 768;
    int gg  = tid / 768;
    int k0  = gg * 8;
    float f[8];
#pragma unroll
    for (int j = 0; j < 8; j++) f[j] = w[(size_t)(k0 + j) * NN + n];
    int nt = n >> 7;
    int nr = n & 127;
    int kt = gg >> 3;
    int g  = gg & 7;
    int gs = g ^ (nr & 7);
    union { __hip_bfloat16 h[8]; uint4 u; } o;
#pragma unroll
    for (int j = 0; j < 8; j++) o.h[j] = __float2bfloat16(f[j]);
    *(uint4*)(wpack + ((size_t)(nt * KT + kt) * BN + nr) * BK + gs * 8) = o.u;
}

// ---------------------------------------------------------------------------
// Phase 2: bf16 MFMA GEMM (m97 structure) + bias + exact GELU epilogue.
// Block = 256 thr (4 waves, 2x2 of 64x64 wave tiles), tile 128x128, BK=64.
// Staging: 16KB A + 16KB B per iter via global_load_lds width=16 (contiguous
// pre-packed tiles). Fragments: ds_read_b128 with xor-swizzled group index.
// ---------------------------------------------------------------------------
__global__ __launch_bounds__(256) void gemm_gelu(const __hip_bfloat16* __restrict__ apack,
                                                 const __hip_bfloat16* __restrict__ wpack,
                                                 const float* __restrict__ bias,
                                                 float* __restrict__ out) {
    __shared__ __align__(16) __hip_bfloat16 As[BM * BK];
    __shared__ __align__(16) __hip_bfloat16 Bs[BN * BK];

    const int mt   = blockIdx.x;
    const int nt   = blockIdx.y;
    const int tid  = threadIdx.x;
    const int lane = tid & 63;
    const int wave = tid >> 6;
    const int wm   = (wave & 1) * 64;
    const int wn   = (wave >> 1) * 64;
    const int col  = lane & 15;
    const int quad = lane >> 4;

    v4f acc[4][4];
    const v4f vzero = {0.f, 0.f, 0.f, 0.f};
#pragma unroll
    for (int a = 0; a < 4; a++)
#pragma unroll
        for (int c = 0; c < 4; c++) acc[a][c] = vzero;

    const char* aT = (const char*)apack + (size_t)mt * KT * TILE_BYTES;
    const char* bT = (const char*)wpack + (size_t)nt * KT * TILE_BYTES;

    for (int kt = 0; kt < KT; kt++) {
        // ---- stage 16KB A-tile + 16KB B-tile (each thread: 4+4 x 16B) ----
#pragma unroll
        for (int p = 0; p < 4; p++) {
            int off = p * 4096 + tid * 16;
            __builtin_amdgcn_global_load_lds(
                (const __attribute__((address_space(1))) void*)(aT + (size_t)kt * TILE_BYTES + off),
                (__attribute__((address_space(3))) void*)((char*)As + off), 16, 0, 0);
            __builtin_amdgcn_global_load_lds(
                (const __attribute__((address_space(1))) void*)(bT + (size_t)kt * TILE_BYTES + off),
                (__attribute__((address_space(3))) void*)((char*)Bs + off), 16, 0, 0);
        }
        __syncthreads();   // compiler drains vmcnt before s_barrier

        // ---- compute: 2 k-steps of 32, 4x4 MFMA tiles per wave ----
#pragma unroll
        for (int ks = 0; ks < 2; ks++) {
            v8bf af[4], bfr[4];
            const int g = ks * 4 + quad;
#pragma unroll
            for (int mi = 0; mi < 4; mi++) {
                int r  = wm + mi * 16 + col;
                int gs = g ^ (r & 7);
                af[mi] = *(const v8bf*)(As + r * BK + gs * 8);
            }
#pragma unroll
            for (int ni = 0; ni < 4; ni++) {
                int r  = wn + ni * 16 + col;
                int gs = g ^ (r & 7);
                bfr[ni] = *(const v8bf*)(Bs + r * BK + gs * 8);
            }
#pragma unroll
            for (int mi = 0; mi < 4; mi++)
#pragma unroll
                for (int ni = 0; ni < 4; ni++)
                    acc[mi][ni] = __builtin_amdgcn_mfma_f32_16x16x32_bf16(
                        af[mi], bfr[ni], acc[mi][ni], 0, 0, 0);
        }
        __syncthreads();
    }

    // ---- epilogue: bias + exact GELU, coalesced fp32 stores ----
#pragma unroll
    for (int ni = 0; ni < 4; ni++) {
        int n   = nt * 128 + wn + ni * 16 + col;
        float bv = bias[n];
#pragma unroll
        for (int mi = 0; mi < 4; mi++) {
            int rowb = mt * 128 + wm + mi * 16 + quad * 4;
            float* po = out + (size_t)rowb * NN + n;
#pragma unroll
            for (int rg = 0; rg < 4; rg++) {
                float x = acc[mi][ni][rg] + bv;
                float y = 0.5f * x * (1.0f + erff(x * 0.70710678118654752f));
                po[(size_t)rg * NN] = y;
            }
        }
    }
}

extern "C" void kernel_launch(void* const* d_in, const int* in_sizes, int n_in,
                              void* d_out, int out_size, void* d_ws, size_t ws_size,
                              hipStream_t stream) {
    const float* img   = (const float*)d_in[0];   // [64,224,224,3]
    const float* wproj = (const float*)d_in[1];   // [768,768]
    const float* bias  = (const float*)d_in[2];   // [768]
    float* out = (float*)d_out;                   // [64,196,768]

    __hip_bfloat16* apack = (__hip_bfloat16*)d_ws;                       // 19,267,584 B
    __hip_bfloat16* wpack = (__hip_bfloat16*)((char*)d_ws + (size_t)MM * KK * 2);
    // total ws need: 20,447,232 B

    im2col_pack<<<dim3((MM * 96) / 256), dim3(256), 0, stream>>>(img, apack);
    wt_pack<<<dim3((NN * 96) / 256), dim3(256), 0, stream>>>(wproj, wpack);
    gemm_gelu<<<dim3(MT, NT), dim3(256), 0, stream>>>(apack, wpack, bias, out);
}

// Round 2
// 123.075 us; speedup vs baseline: 1.0023x; 1.0023x over previous
//
#include <hip/hip_runtime.h>
#include <hip/hip_bf16.h>
#include <math.h>

// Problem constants
#define MM 12544   // 64 * 196 patches
#define KK 768     // 16*16*3
#define NN 768     // embedding dim
#define BM 128
#define BN 128
#define BK 64
#define KT 12      // KK/BK
#define MT 98      // MM/BM
#define NT 6       // NN/BN
#define TILE_BYTES (BM*BK*2)   // 16384

#define IM2COL_BLOCKS ((MM * 96) / 256)   // 4704
#define WTPACK_BLOCKS ((NN * 96) / 256)   // 288

typedef __bf16 v8bf __attribute__((ext_vector_type(8)));
typedef float  v4f  __attribute__((ext_vector_type(4)));

// ---------------------------------------------------------------------------
// Phase 1 (merged): im2col+pack for A, transpose+pack for W. Branch is
// wave-uniform (blockIdx-based). Pack layout: [t][kt][r 0..127][g^(r&7)][8]
// bf16 — the xor swizzle makes the GEMM's ds_read_b128 fragment reads 2-way
// bank-aliased (free, m136) instead of 8-way. global_load_lds staging copies
// tiles verbatim so the swizzle survives.
// ---------------------------------------------------------------------------
__global__ __launch_bounds__(256) void pack_kernel(const float* __restrict__ img,
                                                   const float* __restrict__ w,
                                                   __hip_bfloat16* __restrict__ apack,
                                                   __hip_bfloat16* __restrict__ wpack) {
    if (blockIdx.x < IM2COL_BLOCKS) {
        int tid = blockIdx.x * 256 + threadIdx.x;   // 0 .. 12544*96-1
        int gg  = tid % 96;                         // k-group of 8 within row
        int m   = tid / 96;                         // patch index 0..12543
        int b   = m / 196;
        int pm  = m - b * 196;
        int pr  = pm / 14;
        int pc  = pm - pr * 14;
        int k0  = gg * 8;
        int i   = k0 / 48;                          // row within patch
        int rem = k0 - i * 48;                      // multiple of 8, <48
        const float* src = img + (size_t)(((b * 224 + pr * 16 + i) * 224 + pc * 16) * 3 + rem);
        float4 f0 = *(const float4*)src;
        float4 f1 = *(const float4*)(src + 4);
        int mt = m >> 7;
        int r  = m & 127;
        int kt = gg >> 3;
        int g  = gg & 7;
        int gs = g ^ (r & 7);
        union { __hip_bfloat16 h[8]; uint4 u; } o;
        o.h[0] = __float2bfloat16(f0.x); o.h[1] = __float2bfloat16(f0.y);
        o.h[2] = __float2bfloat16(f0.z); o.h[3] = __float2bfloat16(f0.w);
        o.h[4] = __float2bfloat16(f1.x); o.h[5] = __float2bfloat16(f1.y);
        o.h[6] = __float2bfloat16(f1.z); o.h[7] = __float2bfloat16(f1.w);
        *(uint4*)(apack + ((size_t)(mt * KT + kt) * BM + r) * BK + gs * 8) = o.u;
    } else {
        int tid = (blockIdx.x - IM2COL_BLOCKS) * 256 + threadIdx.x;  // 0 .. 768*96-1
        int n   = tid % 768;
        int gg  = tid / 768;
        int k0  = gg * 8;
        float f[8];
#pragma unroll
        for (int j = 0; j < 8; j++) f[j] = w[(size_t)(k0 + j) * NN + n];
        int nt = n >> 7;
        int nr = n & 127;
        int kt = gg >> 3;
        int g  = gg & 7;
        int gs = g ^ (nr & 7);
        union { __hip_bfloat16 h[8]; uint4 u; } o;
#pragma unroll
        for (int j = 0; j < 8; j++) o.h[j] = __float2bfloat16(f[j]);
        *(uint4*)(wpack + ((size_t)(nt * KT + kt) * BN + nr) * BK + gs * 8) = o.u;
    }
}

// ---------------------------------------------------------------------------
// Phase 2: bf16 MFMA GEMM + bias + exact GELU.
// __launch_bounds__(256,4): cap VGPR at 128 -> 4 blocks/CU -> all 588 blocks
// co-resident (588 < 1024 slots) so barrier drains overlap other blocks' MFMA.
// Simplified LDS addressing: since wm/wn and mi*16 are multiples of 8,
// gs = (ks*4+quad) ^ (col&7); mi/ni become pure ds_read immediate offsets.
// ---------------------------------------------------------------------------
__global__ __launch_bounds__(256, 4) void gemm_gelu(const __hip_bfloat16* __restrict__ apack,
                                                    const __hip_bfloat16* __restrict__ wpack,
                                                    const float* __restrict__ bias,
                                                    float* __restrict__ out) {
    __shared__ __align__(16) __hip_bfloat16 As[BM * BK];
    __shared__ __align__(16) __hip_bfloat16 Bs[BN * BK];

    const int mt   = blockIdx.x;
    const int nt   = blockIdx.y;
    const int tid  = threadIdx.x;
    const int lane = tid & 63;
    const int wave = tid >> 6;
    const int wm   = (wave & 1) * 64;
    const int wn   = (wave >> 1) * 64;
    const int col  = lane & 15;
    const int quad = lane >> 4;
    const int cl7  = col & 7;

    v4f acc[4][4];
    const v4f vzero = {0.f, 0.f, 0.f, 0.f};
#pragma unroll
    for (int a = 0; a < 4; a++)
#pragma unroll
        for (int c = 0; c < 4; c++) acc[a][c] = vzero;

    const char* aT = (const char*)apack + (size_t)mt * KT * TILE_BYTES;
    const char* bT = (const char*)wpack + (size_t)nt * KT * TILE_BYTES;

    for (int kt = 0; kt < KT; kt++) {
        // ---- stage 16KB A-tile + 16KB B-tile (each thread: 4+4 x 16B) ----
#pragma unroll
        for (int p = 0; p < 4; p++) {
            int off = p * 4096 + tid * 16;
            __builtin_amdgcn_global_load_lds(
                (const __attribute__((address_space(1))) void*)(aT + off),
                (__attribute__((address_space(3))) void*)((char*)As + off), 16, 0, 0);
            __builtin_amdgcn_global_load_lds(
                (const __attribute__((address_space(1))) void*)(bT + off),
                (__attribute__((address_space(3))) void*)((char*)Bs + off), 16, 0, 0);
        }
        aT += TILE_BYTES;
        bT += TILE_BYTES;
        __syncthreads();

        // ---- compute: 2 k-steps of 32, 4x4 MFMA tiles per wave ----
#pragma unroll
        for (int ks = 0; ks < 2; ks++) {
            const int gs = (ks * 4 + quad) ^ cl7;
            const v8bf* pa = (const v8bf*)(As + (wm + col) * BK + gs * 8);
            const v8bf* pb = (const v8bf*)(Bs + (wn + col) * BK + gs * 8);
            v8bf af[4], bfr[4];
#pragma unroll
            for (int mi = 0; mi < 4; mi++) af[mi] = pa[mi * 128];   // +2048 B imm
#pragma unroll
            for (int ni = 0; ni < 4; ni++) bfr[ni] = pb[ni * 128];
#pragma unroll
            for (int mi = 0; mi < 4; mi++)
#pragma unroll
                for (int ni = 0; ni < 4; ni++)
                    acc[mi][ni] = __builtin_amdgcn_mfma_f32_16x16x32_bf16(
                        af[mi], bfr[ni], acc[mi][ni], 0, 0, 0);
        }
        __syncthreads();
    }

    // ---- epilogue: bias + exact GELU, coalesced fp32 stores ----
#pragma unroll
    for (int ni = 0; ni < 4; ni++) {
        int n   = nt * 128 + wn + ni * 16 + col;
        float bv = bias[n];
#pragma unroll
        for (int mi = 0; mi < 4; mi++) {
            int rowb = mt * 128 + wm + mi * 16 + quad * 4;
            float* po = out + (size_t)rowb * NN + n;
#pragma unroll
            for (int rg = 0; rg < 4; rg++) {
                float x = acc[mi][ni][rg] + bv;
                float y = 0.5f * x * (1.0f + erff(x * 0.70710678118654752f));
                po[(size_t)rg * NN] = y;
            }
        }
    }
}

extern "C" void kernel_launch(void* const* d_in, const int* in_sizes, int n_in,
                              void* d_out, int out_size, void* d_ws, size_t ws_size,
                              hipStream_t stream) {
    const float* img   = (const float*)d_in[0];   // [64,224,224,3]
    const float* wproj = (const float*)d_in[1];   // [768,768]
    const float* bias  = (const float*)d_in[2];   // [768]
    float* out = (float*)d_out;                   // [64,196,768]

    __hip_bfloat16* apack = (__hip_bfloat16*)d_ws;                       // 19,267,584 B
    __hip_bfloat16* wpack = (__hip_bfloat16*)((char*)d_ws + (size_t)MM * KK * 2);
    // total ws need: 20,447,232 B

    pack_kernel<<<dim3(IM2COL_BLOCKS + WTPACK_BLOCKS), dim3(256), 0, stream>>>(
        img, wproj, apack, wpack);
    gemm_gelu<<<dim3(MT, NT), dim3(256), 0, stream>>>(apack, wpack, bias, out);
}